// Round 2
// baseline (1157.111 us; speedup 1.0000x reference)
//
#include <hip/hip_runtime.h>
#include <math.h>

#define NN 100000
#define MM 20000
#define KINC 640000
#define INDIM 256
#define HIDDIM 128
#define EPSBN 1e-5f

// ---------------- CSR build ----------------

__global__ void hist_kernel(const int* __restrict__ nidx, const int* __restrict__ eidx,
                            const float* __restrict__ w, int* __restrict__ ecnt,
                            int* __restrict__ ncnt, float* __restrict__ D) {
  int stride = gridDim.x * blockDim.x;
  for (int k = blockIdx.x * blockDim.x + threadIdx.x; k < KINC; k += stride) {
    int e = eidx[k], n = nidx[k];
    atomicAdd(&ecnt[e], 1);
    atomicAdd(&ncnt[n], 1);
    atomicAdd(&D[n], w[e]);
  }
}

// Per-segment base offsets via wave-aggregated atomic allocation (no global scan:
// bases need not be ordered, only disjoint). Also emits Binv for edges.
__global__ void base_kernel(const int* __restrict__ cnt, int* __restrict__ ptr,
                            int* __restrict__ pend, float* __restrict__ binv,
                            int* __restrict__ counter, int len) {
  int i = blockIdx.x * blockDim.x + threadIdx.x;
  int lane = threadIdx.x & 63;
  int v = (i < len) ? cnt[i] : 0;
  int s = v;
  #pragma unroll
  for (int off = 1; off < 64; off <<= 1) {
    int t = __shfl_up(s, off);
    if (lane >= off) s += t;
  }
  int total = __shfl(s, 63);
  int base = 0;
  if (lane == 0) base = atomicAdd(counter, total);
  base = __shfl(base, 0);
  if (i < len) {
    ptr[i] = base + s - v;
    pend[i] = base + s;
    if (binv) binv[i] = (v > 0) ? 1.0f / (float)v : 0.0f;
  }
}

// Countdown fill: reuses the histogram counters (atomicSub to 0), no extra zeroing.
__global__ void fill_kernel(const int* __restrict__ nidx, const int* __restrict__ eidx,
                            int* __restrict__ ecnt, int* __restrict__ ncnt,
                            const int* __restrict__ eptr, const int* __restrict__ nptr,
                            int* __restrict__ enodes, int* __restrict__ nedges) {
  int stride = gridDim.x * blockDim.x;
  for (int k = blockIdx.x * blockDim.x + threadIdx.x; k < KINC; k += stride) {
    int e = eidx[k], n = nidx[k];
    int pe = atomicSub(&ecnt[e], 1) - 1;
    enodes[eptr[e] + pe] = n;
    int pn = atomicSub(&ncnt[n], 1) - 1;
    nedges[nptr[n] + pn] = e;
  }
}

__global__ void dinv_kernel(float* __restrict__ D) {
  int i = blockIdx.x * blockDim.x + threadIdx.x;
  if (i < NN) { float d = D[i]; D[i] = (d > 0.0f) ? 1.0f / d : 0.0f; }
}

// ---------------- GEMM: out = act(A @ W + bias), A [nrows,KDIM], W [KDIM,128] ----------------
// Block: 256 thr = 4 waves; 64 rows/block; wave w covers 16 cols (grid.y picks col half).
// x^T staged in LDS (conflict-free b32 broadcast reads); W streamed via wave-uniform
// scalar loads (SGPR operand in v_fma) -> 16 FMA per LDS read.
template<int KDIM, bool RELU, bool DUP>
__global__ __launch_bounds__(256) void gemm_kernel(const float* __restrict__ A,
    const float* __restrict__ W, const float* __restrict__ bias,
    float* __restrict__ out, float* __restrict__ out2, int nrows) {
  __shared__ float xT[128 * 64];
  const int t = threadIdx.x;
  const int lane = t & 63;
  const int wv = __builtin_amdgcn_readfirstlane(t >> 6);
  const int r0 = blockIdx.x * 64;
  const int c0 = (blockIdx.y * 4 + wv) * 16;
  float acc[16];
  #pragma unroll
  for (int c = 0; c < 16; ++c) acc[c] = 0.0f;

  for (int kc = 0; kc < KDIM; kc += 128) {
    __syncthreads();
    #pragma unroll
    for (int i = 0; i < 8; ++i) {
      int f4 = t + i * 256;
      int row = f4 & 63;          // = lane (contiguous per wave -> conflict-free ds_write)
      int k4 = f4 >> 6;           // 0..31
      int gr = r0 + row;
      float4 v = make_float4(0.f, 0.f, 0.f, 0.f);
      if (gr < nrows) v = *(const float4*)(A + (size_t)gr * KDIM + kc + k4 * 4);
      xT[(k4 * 4 + 0) * 64 + row] = v.x;
      xT[(k4 * 4 + 1) * 64 + row] = v.y;
      xT[(k4 * 4 + 2) * 64 + row] = v.z;
      xT[(k4 * 4 + 3) * 64 + row] = v.w;
    }
    __syncthreads();
    const float* Wc = W + (size_t)kc * HIDDIM + c0;
    #pragma unroll 4
    for (int kk = 0; kk < 128; ++kk) {
      float xv = xT[kk * 64 + lane];
      const float* wr = Wc + kk * HIDDIM;   // wave-uniform -> s_load
      #pragma unroll
      for (int c = 0; c < 16; ++c) acc[c] = fmaf(xv, wr[c], acc[c]);
    }
  }
  int row = r0 + lane;
  if (row < nrows) {
    float* o = out + (size_t)row * HIDDIM + c0;
    #pragma unroll
    for (int c = 0; c < 16; ++c) {
      float v = acc[c] + bias[c0 + c];
      if (RELU) v = fmaxf(v, 0.0f);
      o[c] = v;
      if (DUP) out2[(size_t)row * HIDDIM + c0 + c] = v;
    }
  }
}

// ---------------- per-column sum / sumsq for BatchNorm ----------------
__global__ __launch_bounds__(256) void stats_kernel(const float* __restrict__ x,
    float* __restrict__ out, int n) {
  __shared__ float lsum[128], lsq[128];
  int t = threadIdx.x;
  int lane = t & 63, wv = t >> 6;
  if (t < 128) { lsum[t] = 0.f; lsq[t] = 0.f; }
  __syncthreads();
  float sx = 0, sy = 0, qx = 0, qy = 0;
  const float2* x2 = (const float2*)x;
  for (int r = blockIdx.x * 4 + wv; r < n; r += gridDim.x * 4) {
    float2 v = x2[(size_t)r * 64 + lane];
    sx += v.x; sy += v.y; qx += v.x * v.x; qy += v.y * v.y;
  }
  atomicAdd(&lsum[2 * lane], sx);
  atomicAdd(&lsum[2 * lane + 1], sy);
  atomicAdd(&lsq[2 * lane], qx);
  atomicAdd(&lsq[2 * lane + 1], qy);
  __syncthreads();
  if (t < 128) {
    atomicAdd(&out[t], lsum[t]);
    atomicAdd(&out[128 + t], lsq[t]);
  }
}

// ---------------- fold BN into conv weight: W' = diag(gamma*s)*W, b' = c @ W ----------------
__global__ void prep_kernel(const float* __restrict__ stats, const float* __restrict__ gamma,
    const float* __restrict__ beta, const float* __restrict__ Wc,
    float* __restrict__ Wp, float* __restrict__ bp) {
  __shared__ float al[128], cc[128];
  int t = threadIdx.x;
  {
    float mu = stats[t] * (1.0f / NN);
    float var = stats[128 + t] * (1.0f / NN) - mu * mu;
    var = fmaxf(var, 0.0f);
    float s = rsqrtf(var + EPSBN);
    float a = gamma[t] * s;
    al[t] = a;
    cc[t] = beta[t] - mu * a;
  }
  __syncthreads();
  for (int idx = t; idx < 128 * 128; idx += 128)
    Wp[idx] = al[idx >> 7] * Wc[idx];
  float b = 0.f;
  for (int k = 0; k < 128; ++k) b = fmaf(cc[k], Wc[k * 128 + t], b);
  bp[t] = b;
}

// ---------------- e = Binv * segsum(xw[nodes]) : one wave per edge ----------------
__global__ __launch_bounds__(256) void edge_agg_kernel(const float* __restrict__ xw,
    const int* __restrict__ eptr, const int* __restrict__ pend,
    const int* __restrict__ enodes, const float* __restrict__ binv,
    float* __restrict__ e2) {
  int gw = (blockIdx.x * 256 + threadIdx.x) >> 6;
  int lane = threadIdx.x & 63;
  int e = __builtin_amdgcn_readfirstlane(gw);
  if (e >= MM) return;
  int p0 = eptr[e], p1 = pend[e];
  const float2* xw2 = (const float2*)xw;
  float ax = 0, ay = 0, bx = 0, by = 0;
  int j = p0;
  for (; j + 2 <= p1; j += 2) {
    int n0 = enodes[j], n1 = enodes[j + 1];
    float2 v0 = xw2[(size_t)n0 * 64 + lane];
    float2 v1 = xw2[(size_t)n1 * 64 + lane];
    ax += v0.x; ay += v0.y; bx += v1.x; by += v1.y;
  }
  if (j < p1) {
    int n0 = enodes[j];
    float2 v0 = xw2[(size_t)n0 * 64 + lane];
    ax += v0.x; ay += v0.y;
  }
  float bi = binv[e];
  float2 r; r.x = (ax + bx) * bi; r.y = (ay + by) * bi;
  ((float2*)e2)[(size_t)e * 64 + lane] = r;
}

// ---------------- node update: h=relu(Dinv*segsum(e)+bconv), gate, residual ----------------
template<bool LAST>
__global__ __launch_bounds__(256) void node_agg_kernel(const float* __restrict__ e2,
    const int* __restrict__ nptr, const int* __restrict__ pend,
    const int* __restrict__ nedges, const float* __restrict__ dinv,
    const float* __restrict__ bconv, const float* __restrict__ wgate,
    const float* __restrict__ bgate, const float* __restrict__ x,
    float* __restrict__ xout, const float* __restrict__ idres, float* __restrict__ fout) {
  int gw = (blockIdx.x * 256 + threadIdx.x) >> 6;
  int lane = threadIdx.x & 63;
  int nid = __builtin_amdgcn_readfirstlane(gw);
  if (nid >= NN) return;
  int p0 = nptr[nid], p1 = pend[nid];
  const float2* e22 = (const float2*)e2;
  float ax = 0, ay = 0;
  for (int j = p0; j < p1; ++j) {
    int e = nedges[j];
    float2 v = e22[(size_t)e * 64 + lane];
    ax += v.x; ay += v.y;
  }
  float di = dinv[nid];
  float2 xv = ((const float2*)x)[(size_t)nid * 64 + lane];
  float2 wg = ((const float2*)wgate)[lane];
  float part = xv.x * wg.x + xv.y * wg.y;
  #pragma unroll
  for (int off = 32; off >= 1; off >>= 1) part += __shfl_xor(part, off);
  float g = 1.0f / (1.0f + expf(-(part + bgate[0])));
  float2 bc = ((const float2*)bconv)[lane];
  float hx = fmaxf(fmaf(ax, di, bc.x), 0.0f);
  float hy = fmaxf(fmaf(ay, di, bc.y), 0.0f);
  float2 xn; xn.x = fmaf(hx, g, xv.x); xn.y = fmaf(hy, g, xv.y);
  if (LAST) {
    float2 idv = ((const float2*)idres)[(size_t)nid * 64 + lane];
    float2 o; o.x = 2.0f * xn.x + idv.x; o.y = 2.0f * xn.y + idv.y;
    ((float2*)fout)[(size_t)nid * 64 + lane] = o;
  } else {
    ((float2*)xout)[(size_t)nid * 64 + lane] = xn;
  }
}

extern "C" void kernel_launch(void* const* d_in, const int* in_sizes, int n_in,
                              void* d_out, int out_size, void* d_ws, size_t ws_size,
                              hipStream_t stream) {
  const float* X      = (const float*)d_in[0];
  const int*   nidx   = (const int*)d_in[1];
  const int*   eidx   = (const int*)d_in[2];
  const float* hw     = (const float*)d_in[3];
  const float* W_up   = (const float*)d_in[4];
  const float* b_up   = (const float*)d_in[5];
  const float* gamma  = (const float*)d_in[6];
  const float* beta   = (const float*)d_in[7];
  const float* W_conv = (const float*)d_in[8];
  const float* b_conv = (const float*)d_in[9];
  const float* W_gate = (const float*)d_in[10];
  const float* b_gate = (const float*)d_in[11];
  float* out = (float*)d_out;

  char* ws = (char*)d_ws;
  size_t off = 0;
  auto alloc = [&](size_t bytes) -> void* {
    void* p = ws + off;
    off = (off + bytes + 255) & ~(size_t)255;
    return p;
  };
  // ---- zero region (single memset) ----
  float* D     = (float*)alloc((size_t)NN * 4);
  int*   ecnt  = (int*)alloc((size_t)MM * 4);
  int*   ncnt  = (int*)alloc((size_t)NN * 4);
  int*   ctrs  = (int*)alloc(256);
  float* stats = (float*)alloc(3 * 256 * 4);
  size_t zero_bytes = off;
  // ---- rest ----
  int*   eptr   = (int*)alloc((size_t)MM * 4);
  int*   epend  = (int*)alloc((size_t)MM * 4);
  int*   nptr   = (int*)alloc((size_t)NN * 4);
  int*   npend  = (int*)alloc((size_t)NN * 4);
  float* Binv   = (float*)alloc((size_t)MM * 4);
  int*   enodes = (int*)alloc((size_t)KINC * 4);
  int*   nedges = (int*)alloc((size_t)KINC * 4);
  float* x      = (float*)alloc((size_t)NN * HIDDIM * 4);
  float* idr    = (float*)alloc((size_t)NN * HIDDIM * 4);
  float* e2     = (float*)alloc((size_t)MM * HIDDIM * 4);
  float* Wp     = (float*)alloc((size_t)HIDDIM * HIDDIM * 4);
  float* bp     = (float*)alloc((size_t)HIDDIM * 4);
  float* xw     = out;   // reuse output buffer as xW scratch (consumed before final write)

  hipMemsetAsync(d_ws, 0, zero_bytes, stream);
  hist_kernel<<<512, 256, 0, stream>>>(nidx, eidx, hw, ecnt, ncnt, D);
  base_kernel<<<(MM + 255) / 256, 256, 0, stream>>>(ecnt, eptr, epend, Binv, ctrs + 0, MM);
  base_kernel<<<(NN + 255) / 256, 256, 0, stream>>>(ncnt, nptr, npend, nullptr, ctrs + 1, NN);
  fill_kernel<<<512, 256, 0, stream>>>(nidx, eidx, ecnt, ncnt, eptr, nptr, enodes, nedges);
  dinv_kernel<<<(NN + 255) / 256, 256, 0, stream>>>(D);

  dim3 ggrid((NN + 63) / 64, 2);
  gemm_kernel<INDIM, true, true><<<ggrid, 256, 0, stream>>>(X, W_up, b_up, x, idr, NN);

  for (int i = 0; i < 3; ++i) {
    stats_kernel<<<256, 256, 0, stream>>>(x, stats + i * 256, NN);
    prep_kernel<<<1, 128, 0, stream>>>(stats + i * 256, gamma + i * 128, beta + i * 128,
                                       W_conv + (size_t)i * 128 * 128, Wp, bp);
    gemm_kernel<HIDDIM, false, false><<<ggrid, 256, 0, stream>>>(x, Wp, bp, xw, nullptr, NN);
    edge_agg_kernel<<<MM / 4, 256, 0, stream>>>(xw, eptr, epend, enodes, Binv, e2);
    if (i < 2)
      node_agg_kernel<false><<<NN / 4, 256, 0, stream>>>(e2, nptr, npend, nedges, D,
          b_conv + i * 128, W_gate + i * 128, b_gate + i, x, x, nullptr, nullptr);
    else
      node_agg_kernel<true><<<NN / 4, 256, 0, stream>>>(e2, nptr, npend, nedges, D,
          b_conv + i * 128, W_gate + i * 128, b_gate + i, x, nullptr, idr, out);
  }
}

// Round 6
// 1042.274 us; speedup vs baseline: 1.1102x; 1.1102x over previous
//
#include <hip/hip_runtime.h>
#include <math.h>

#define NN 100000
#define MM 20000
#define KINC 640000
#define INDIM 256
#define HIDDIM 128
#define EPSBN 1e-5f

typedef __attribute__((ext_vector_type(4))) float f32x4;
typedef __attribute__((ext_vector_type(8))) short bf16x8;
typedef unsigned short ushort_t;

// round-to-nearest-even fp32 -> bf16 bits
__device__ inline unsigned f2bf_bits(float f) {
  unsigned u = __float_as_uint(f);
  return u + 0x7FFFu + ((u >> 16) & 1u);
}
__device__ inline void split1(float f, ushort_t& hi, ushort_t& lo) {
  unsigned rh = f2bf_bits(f) & 0xFFFF0000u;
  hi = (ushort_t)(rh >> 16);
  float d = f - __uint_as_float(rh);
  lo = (ushort_t)(f2bf_bits(d) >> 16);
}

// ---------------- CSR build ----------------

__global__ void hist_kernel(const int* __restrict__ nidx, const int* __restrict__ eidx,
                            const float* __restrict__ w, int* __restrict__ ecnt,
                            int* __restrict__ ncnt, float* __restrict__ D) {
  int stride = gridDim.x * blockDim.x;
  for (int k = blockIdx.x * blockDim.x + threadIdx.x; k < KINC; k += stride) {
    int e = eidx[k], n = nidx[k];
    atomicAdd(&ecnt[e], 1);
    atomicAdd(&ncnt[n], 1);
    atomicAdd(&D[n], w[e]);
  }
}

__global__ void base_kernel(const int* __restrict__ cnt, int* __restrict__ ptr,
                            int* __restrict__ pend, float* __restrict__ binv,
                            int* __restrict__ counter, int len) {
  int i = blockIdx.x * blockDim.x + threadIdx.x;
  int lane = threadIdx.x & 63;
  int v = (i < len) ? cnt[i] : 0;
  int s = v;
  #pragma unroll
  for (int off = 1; off < 64; off <<= 1) {
    int t = __shfl_up(s, off);
    if (lane >= off) s += t;
  }
  int total = __shfl(s, 63);
  int base = 0;
  if (lane == 0) base = atomicAdd(counter, total);
  base = __shfl(base, 0);
  if (i < len) {
    ptr[i] = base + s - v;
    pend[i] = base + s;
    if (binv) binv[i] = (v > 0) ? 1.0f / (float)v : 0.0f;
  }
}

__global__ void fill_kernel(const int* __restrict__ nidx, const int* __restrict__ eidx,
                            int* __restrict__ ecnt, int* __restrict__ ncnt,
                            const int* __restrict__ eptr, const int* __restrict__ nptr,
                            int* __restrict__ enodes, int* __restrict__ nedges) {
  int stride = gridDim.x * blockDim.x;
  for (int k = blockIdx.x * blockDim.x + threadIdx.x; k < KINC; k += stride) {
    int e = eidx[k], n = nidx[k];
    int pe = atomicSub(&ecnt[e], 1) - 1;
    enodes[eptr[e] + pe] = n;
    int pn = atomicSub(&ncnt[n], 1) - 1;
    nedges[nptr[n] + pn] = e;
  }
}

__global__ void dinv_kernel(float* __restrict__ D) {
  int i = blockIdx.x * blockDim.x + threadIdx.x;
  if (i < NN) { float d = D[i]; D[i] = (d > 0.0f) ? 1.0f / d : 0.0f; }
}

// ---------------- weight prep: transpose + bf16 split ----------------
// W_up [256][128] -> WT_hi/lo [128][256]
__global__ void wsplit_up_kernel(const float* __restrict__ W, ushort_t* __restrict__ Th,
                                 ushort_t* __restrict__ Tl) {
  int idx = blockIdx.x * 256 + threadIdx.x;   // 128*256 elems, grid 128
  int c = idx >> 8, k = idx & 255;
  ushort_t h, l;
  split1(W[k * HIDDIM + c], h, l);
  Th[c * INDIM + k] = h;
  Tl[c * INDIM + k] = l;
}

// BN-folded conv weight: WT' = (diag(gamma*s)*Wc)^T split to bf16 hi/lo, b' = c @ Wc
__global__ void prep_kernel(const float* __restrict__ stats, const float* __restrict__ gamma,
    const float* __restrict__ beta, const float* __restrict__ Wc,
    ushort_t* __restrict__ Th, ushort_t* __restrict__ Tl, float* __restrict__ bp) {
  __shared__ float al[128], cc[128];
  int t = threadIdx.x;  // 256 threads, 1 block
  if (t < 128) {
    float mu = stats[t] * (1.0f / NN);
    float var = fmaxf(stats[128 + t] * (1.0f / NN) - mu * mu, 0.0f);
    float a = gamma[t] * rsqrtf(var + EPSBN);
    al[t] = a;
    cc[t] = beta[t] - mu * a;
  }
  __syncthreads();
  for (int idx = t; idx < 128 * 128; idx += 256) {
    int c = idx >> 7, k = idx & 127;
    ushort_t h, l;
    split1(al[k] * Wc[k * 128 + c], h, l);
    Th[c * 128 + k] = h;
    Tl[c * 128 + k] = l;
  }
  if (t < 128) {
    float b = 0.f;
    for (int k = 0; k < 128; ++k) b = fmaf(cc[k], Wc[k * 128 + t], b);
    bp[t] = b;
  }
}

// ---------------- MFMA GEMM: out = act(A @ W + bias) via bf16 split ----------------
// A [nrows][KDIM] fp32; BT_hi/lo [128][KDIM] bf16 bits (pre-transposed).
// Block: 4 waves, 128 rows, all 128 cols. Wave w: row-tiles r0+w*16 and r0+64+w*16.
// mfma_f32_16x16x32_bf16: A-frag lane l: row=l&15, k=(l>>4)*8+j; B-frag: col=l&15, same k.
// C/D: col=lane&15, row=(lane>>4)*4+reg  [m89-verified].
template<int KDIM, bool RELU, bool DUP>
__global__ __launch_bounds__(256) void mgemm_kernel(const float* __restrict__ A,
    const ushort_t* __restrict__ BTh, const ushort_t* __restrict__ BTl,
    const float* __restrict__ bias, float* __restrict__ out, float* __restrict__ out2,
    int nrows) {
  const int lane = threadIdx.x & 63;
  const int wv = threadIdx.x >> 6;
  const int m = lane & 15;
  const int kg = lane >> 4;
  const int r0 = blockIdx.x * 128;
  const int rt0 = r0 + wv * 16;
  const int rt1 = r0 + 64 + wv * 16;

  f32x4 acc0[8], acc1[8];
  #pragma unroll
  for (int ct = 0; ct < 8; ++ct) {
    acc0[ct] = (f32x4){0.f, 0.f, 0.f, 0.f};
    acc1[ct] = (f32x4){0.f, 0.f, 0.f, 0.f};
  }
  float bv[8];
  #pragma unroll
  for (int ct = 0; ct < 8; ++ct) bv[ct] = bias[ct * 16 + m];

  const int row0 = rt0 + m, row1 = rt1 + m;
  const bool v0 = row0 < nrows, v1 = row1 < nrows;
  const float* a0p = A + (size_t)row0 * KDIM + kg * 8;
  const float* a1p = A + (size_t)row1 * KDIM + kg * 8;

  for (int ks = 0; ks < KDIM; ks += 32) {
    float a0[8] = {0, 0, 0, 0, 0, 0, 0, 0}, a1[8] = {0, 0, 0, 0, 0, 0, 0, 0};
    if (v0) {
      *(float4*)(a0) = *(const float4*)(a0p + ks);
      *(float4*)(a0 + 4) = *(const float4*)(a0p + ks + 4);
    }
    if (v1) {
      *(float4*)(a1) = *(const float4*)(a1p + ks);
      *(float4*)(a1 + 4) = *(const float4*)(a1p + ks + 4);
    }
    bf16x8 a0h, a0l, a1h, a1l;
    #pragma unroll
    for (int j = 0; j < 8; ++j) {
      ushort_t h, l;
      split1(a0[j], h, l); a0h[j] = (short)h; a0l[j] = (short)l;
      split1(a1[j], h, l); a1h[j] = (short)h; a1l[j] = (short)l;
    }
    #pragma unroll
    for (int ct = 0; ct < 8; ++ct) {
      size_t bo = (size_t)(ct * 16 + m) * KDIM + ks + kg * 8;
      bf16x8 bh = *(const bf16x8*)(BTh + bo);
      bf16x8 bl = *(const bf16x8*)(BTl + bo);
      acc0[ct] = __builtin_amdgcn_mfma_f32_16x16x32_bf16(a0h, bh, acc0[ct], 0, 0, 0);
      acc0[ct] = __builtin_amdgcn_mfma_f32_16x16x32_bf16(a0l, bh, acc0[ct], 0, 0, 0);
      acc0[ct] = __builtin_amdgcn_mfma_f32_16x16x32_bf16(a0h, bl, acc0[ct], 0, 0, 0);
      acc1[ct] = __builtin_amdgcn_mfma_f32_16x16x32_bf16(a1h, bh, acc1[ct], 0, 0, 0);
      acc1[ct] = __builtin_amdgcn_mfma_f32_16x16x32_bf16(a1l, bh, acc1[ct], 0, 0, 0);
      acc1[ct] = __builtin_amdgcn_mfma_f32_16x16x32_bf16(a1h, bl, acc1[ct], 0, 0, 0);
    }
  }
  #pragma unroll
  for (int ct = 0; ct < 8; ++ct) {
    #pragma unroll
    for (int j = 0; j < 4; ++j) {
      int r = rt0 + kg * 4 + j;
      if (r < nrows) {
        float v = acc0[ct][j] + bv[ct];
        if (RELU) v = fmaxf(v, 0.0f);
        out[(size_t)r * HIDDIM + ct * 16 + m] = v;
        if (DUP) out2[(size_t)r * HIDDIM + ct * 16 + m] = v;
      }
      r = rt1 + kg * 4 + j;
      if (r < nrows) {
        float v = acc1[ct][j] + bv[ct];
        if (RELU) v = fmaxf(v, 0.0f);
        out[(size_t)r * HIDDIM + ct * 16 + m] = v;
        if (DUP) out2[(size_t)r * HIDDIM + ct * 16 + m] = v;
      }
    }
  }
}

// ---------------- per-column sum / sumsq for BatchNorm (layer 0 only) ----------------
__global__ __launch_bounds__(256) void stats_kernel(const float* __restrict__ x,
    float* __restrict__ out, int n) {
  __shared__ float lsum[128], lsq[128];
  int t = threadIdx.x;
  int lane = t & 63, wv = t >> 6;
  if (t < 128) { lsum[t] = 0.f; lsq[t] = 0.f; }
  __syncthreads();
  float sx = 0, sy = 0, qx = 0, qy = 0;
  const float2* x2 = (const float2*)x;
  for (int r = blockIdx.x * 4 + wv; r < n; r += gridDim.x * 4) {
    float2 v = x2[(size_t)r * 64 + lane];
    sx += v.x; sy += v.y; qx += v.x * v.x; qy += v.y * v.y;
  }
  atomicAdd(&lsum[2 * lane], sx);
  atomicAdd(&lsum[2 * lane + 1], sy);
  atomicAdd(&lsq[2 * lane], qx);
  atomicAdd(&lsq[2 * lane + 1], qy);
  __syncthreads();
  if (t < 128) {
    atomicAdd(&out[t], lsum[t]);
    atomicAdd(&out[128 + t], lsq[t]);
  }
}

// ---------------- e = Binv * segsum(xw[nodes]) : one wave per edge ----------------
__global__ __launch_bounds__(256) void edge_agg_kernel(const float* __restrict__ xw,
    const int* __restrict__ eptr, const int* __restrict__ pend,
    const int* __restrict__ enodes, const float* __restrict__ binv,
    float* __restrict__ e2) {
  int gw = (blockIdx.x * 256 + threadIdx.x) >> 6;
  int lane = threadIdx.x & 63;
  int e = __builtin_amdgcn_readfirstlane(gw);
  if (e >= MM) return;
  int p0 = eptr[e], p1 = pend[e];
  const float2* xw2 = (const float2*)xw;
  float ax = 0, ay = 0, bx = 0, by = 0;
  int j = p0;
  for (; j + 2 <= p1; j += 2) {
    int n0 = enodes[j], n1 = enodes[j + 1];
    float2 v0 = xw2[(size_t)n0 * 64 + lane];
    float2 v1 = xw2[(size_t)n1 * 64 + lane];
    ax += v0.x; ay += v0.y; bx += v1.x; by += v1.y;
  }
  if (j < p1) {
    int n0 = enodes[j];
    float2 v0 = xw2[(size_t)n0 * 64 + lane];
    ax += v0.x; ay += v0.y;
  }
  float bi = binv[e];
  float2 r; r.x = (ax + bx) * bi; r.y = (ay + by) * bi;
  ((float2*)e2)[(size_t)e * 64 + lane] = r;
}

// ---------------- node update + fused BN stats for next layer ----------------
template<bool LAST>
__global__ __launch_bounds__(256) void node_agg_kernel(const float* __restrict__ e2,
    const int* __restrict__ nptr, const int* __restrict__ pend,
    const int* __restrict__ nedges, const float* __restrict__ dinv,
    const float* __restrict__ bconv, const float* __restrict__ wgate,
    const float* __restrict__ bgate, const float* __restrict__ x,
    float* __restrict__ xout, const float* __restrict__ idres, float* __restrict__ fout,
    float* __restrict__ stats_out) {
  __shared__ float ls[256];
  int t = threadIdx.x;
  int lane = t & 63, wv = t >> 6;
  ls[t] = 0.f;
  __syncthreads();
  float sx = 0, sy = 0, qx = 0, qy = 0;
  const float2* e22 = (const float2*)e2;
  for (int nid0 = blockIdx.x * 4 + wv; nid0 < NN; nid0 += gridDim.x * 4) {
    int nid = __builtin_amdgcn_readfirstlane(nid0);
    int p0 = nptr[nid], p1 = pend[nid];
    float ax = 0, ay = 0;
    for (int j = p0; j < p1; ++j) {
      int e = nedges[j];
      float2 v = e22[(size_t)e * 64 + lane];
      ax += v.x; ay += v.y;
    }
    float di = dinv[nid];
    float2 xv = ((const float2*)x)[(size_t)nid * 64 + lane];
    float2 wg = ((const float2*)wgate)[lane];
    float part = xv.x * wg.x + xv.y * wg.y;
    #pragma unroll
    for (int off = 32; off >= 1; off >>= 1) part += __shfl_xor(part, off);
    float g = 1.0f / (1.0f + expf(-(part + bgate[0])));
    float2 bc = ((const float2*)bconv)[lane];
    float hx = fmaxf(fmaf(ax, di, bc.x), 0.0f);
    float hy = fmaxf(fmaf(ay, di, bc.y), 0.0f);
    float2 xn; xn.x = fmaf(hx, g, xv.x); xn.y = fmaf(hy, g, xv.y);
    if (LAST) {
      float2 idv = ((const float2*)idres)[(size_t)nid * 64 + lane];
      float2 o; o.x = 2.0f * xn.x + idv.x; o.y = 2.0f * xn.y + idv.y;
      ((float2*)fout)[(size_t)nid * 64 + lane] = o;
    } else {
      ((float2*)xout)[(size_t)nid * 64 + lane] = xn;
      sx += xn.x; sy += xn.y; qx += xn.x * xn.x; qy += xn.y * xn.y;
    }
  }
  if (!LAST) {
    atomicAdd(&ls[2 * lane], sx);
    atomicAdd(&ls[2 * lane + 1], sy);
    atomicAdd(&ls[128 + 2 * lane], qx);
    atomicAdd(&ls[128 + 2 * lane + 1], qy);
    __syncthreads();
    atomicAdd(&stats_out[t], ls[t]);
  }
}

extern "C" void kernel_launch(void* const* d_in, const int* in_sizes, int n_in,
                              void* d_out, int out_size, void* d_ws, size_t ws_size,
                              hipStream_t stream) {
  const float* X      = (const float*)d_in[0];
  const int*   nidx   = (const int*)d_in[1];
  const int*   eidx   = (const int*)d_in[2];
  const float* hw     = (const float*)d_in[3];
  const float* W_up   = (const float*)d_in[4];
  const float* b_up   = (const float*)d_in[5];
  const float* gamma  = (const float*)d_in[6];
  const float* beta   = (const float*)d_in[7];
  const float* W_conv = (const float*)d_in[8];
  const float* b_conv = (const float*)d_in[9];
  const float* W_gate = (const float*)d_in[10];
  const float* b_gate = (const float*)d_in[11];
  float* out = (float*)d_out;

  char* ws = (char*)d_ws;
  size_t off = 0;
  auto alloc = [&](size_t bytes) -> void* {
    void* p = ws + off;
    off = (off + bytes + 255) & ~(size_t)255;
    return p;
  };
  // ---- zero region (single memset) ----
  float* D     = (float*)alloc((size_t)NN * 4);
  int*   ecnt  = (int*)alloc((size_t)MM * 4);
  int*   ncnt  = (int*)alloc((size_t)NN * 4);
  int*   ctrs  = (int*)alloc(256);
  float* stats = (float*)alloc(3 * 256 * 4);
  size_t zero_bytes = off;
  // ---- rest ----
  int*   eptr   = (int*)alloc((size_t)MM * 4);
  int*   epend  = (int*)alloc((size_t)MM * 4);
  int*   nptr   = (int*)alloc((size_t)NN * 4);
  int*   npend  = (int*)alloc((size_t)NN * 4);
  float* Binv   = (float*)alloc((size_t)MM * 4);
  int*   enodes = (int*)alloc((size_t)KINC * 4);
  int*   nedges = (int*)alloc((size_t)KINC * 4);
  float* x      = (float*)alloc((size_t)NN * HIDDIM * 4);
  float* idr    = (float*)alloc((size_t)NN * HIDDIM * 4);
  float* e2     = (float*)alloc((size_t)MM * HIDDIM * 4);
  ushort_t* WupTh = (ushort_t*)alloc((size_t)HIDDIM * INDIM * 2);
  ushort_t* WupTl = (ushort_t*)alloc((size_t)HIDDIM * INDIM * 2);
  ushort_t* WTh   = (ushort_t*)alloc((size_t)HIDDIM * HIDDIM * 2);
  ushort_t* WTl   = (ushort_t*)alloc((size_t)HIDDIM * HIDDIM * 2);
  float* bp     = (float*)alloc((size_t)HIDDIM * 4);
  float* xw     = out;   // reuse output buffer as xW scratch (consumed before final write)

  hipMemsetAsync(d_ws, 0, zero_bytes, stream);
  hist_kernel<<<512, 256, 0, stream>>>(nidx, eidx, hw, ecnt, ncnt, D);
  base_kernel<<<(MM + 255) / 256, 256, 0, stream>>>(ecnt, eptr, epend, Binv, ctrs + 0, MM);
  base_kernel<<<(NN + 255) / 256, 256, 0, stream>>>(ncnt, nptr, npend, nullptr, ctrs + 1, NN);
  fill_kernel<<<512, 256, 0, stream>>>(nidx, eidx, ecnt, ncnt, eptr, nptr, enodes, nedges);
  dinv_kernel<<<(NN + 255) / 256, 256, 0, stream>>>(D);
  wsplit_up_kernel<<<128, 256, 0, stream>>>(W_up, WupTh, WupTl);

  mgemm_kernel<INDIM, true, true><<<(NN + 127) / 128, 256, 0, stream>>>(
      X, WupTh, WupTl, b_up, x, idr, NN);
  stats_kernel<<<256, 256, 0, stream>>>(x, stats + 0, NN);

  for (int i = 0; i < 3; ++i) {
    prep_kernel<<<1, 256, 0, stream>>>(stats + i * 256, gamma + i * 128, beta + i * 128,
                                       W_conv + (size_t)i * 128 * 128, WTh, WTl, bp);
    mgemm_kernel<HIDDIM, false, false><<<(NN + 127) / 128, 256, 0, stream>>>(
        x, WTh, WTl, bp, xw, nullptr, NN);
    edge_agg_kernel<<<MM / 4, 256, 0, stream>>>(xw, eptr, epend, enodes, Binv, e2);
    if (i < 2)
      node_agg_kernel<false><<<1280, 256, 0, stream>>>(e2, nptr, npend, nedges, D,
          b_conv + i * 128, W_gate + i * 128, b_gate + i, x, x, nullptr, nullptr,
          stats + (i + 1) * 256);
    else
      node_agg_kernel<true><<<1280, 256, 0, stream>>>(e2, nptr, npend, nedges, D,
          b_conv + i * 128, W_gate + i * 128, b_gate + i, x, nullptr, idr, out, nullptr);
  }
}

// Round 7
// 924.660 us; speedup vs baseline: 1.2514x; 1.1272x over previous
//
#include <hip/hip_runtime.h>
#include <math.h>

#define NN 100000
#define MM 20000
#define KINC 640000
#define INDIM 256
#define HIDDIM 128
#define EPSBN 1e-5f

typedef __attribute__((ext_vector_type(4))) float f32x4;
typedef __attribute__((ext_vector_type(8))) short bf16x8;
typedef unsigned short ushort_t;

// round-to-nearest-even fp32 -> bf16 bits
__device__ inline unsigned f2bf_bits(float f) {
  unsigned u = __float_as_uint(f);
  return u + 0x7FFFu + ((u >> 16) & 1u);
}
__device__ inline void split1(float f, ushort_t& hi, ushort_t& lo) {
  unsigned rh = f2bf_bits(f) & 0xFFFF0000u;
  hi = (ushort_t)(rh >> 16);
  float d = f - __uint_as_float(rh);
  lo = (ushort_t)(f2bf_bits(d) >> 16);
}

// ---------------- CSR build ----------------

__global__ void hist_kernel(const int* __restrict__ nidx, const int* __restrict__ eidx,
                            const float* __restrict__ w, int* __restrict__ ecnt,
                            int* __restrict__ ncnt, float* __restrict__ D) {
  int stride = gridDim.x * blockDim.x;
  for (int k = blockIdx.x * blockDim.x + threadIdx.x; k < KINC; k += stride) {
    int e = eidx[k], n = nidx[k];
    atomicAdd(&ecnt[e], 1);
    atomicAdd(&ncnt[n], 1);
    atomicAdd(&D[n], w[e]);
  }
}

__global__ void base_kernel(const int* __restrict__ cnt, int* __restrict__ ptr,
                            int* __restrict__ pend, float* __restrict__ binv,
                            int* __restrict__ counter, int len) {
  int i = blockIdx.x * blockDim.x + threadIdx.x;
  int lane = threadIdx.x & 63;
  int v = (i < len) ? cnt[i] : 0;
  int s = v;
  #pragma unroll
  for (int off = 1; off < 64; off <<= 1) {
    int t = __shfl_up(s, off);
    if (lane >= off) s += t;
  }
  int total = __shfl(s, 63);
  int base = 0;
  if (lane == 0) base = atomicAdd(counter, total);
  base = __shfl(base, 0);
  if (i < len) {
    ptr[i] = base + s - v;
    pend[i] = base + s;
    if (binv) binv[i] = (v > 0) ? 1.0f / (float)v : 0.0f;
  }
}

__global__ void fill_kernel(const int* __restrict__ nidx, const int* __restrict__ eidx,
                            int* __restrict__ ecnt, int* __restrict__ ncnt,
                            const int* __restrict__ eptr, const int* __restrict__ nptr,
                            int* __restrict__ enodes, int* __restrict__ nedges) {
  int stride = gridDim.x * blockDim.x;
  for (int k = blockIdx.x * blockDim.x + threadIdx.x; k < KINC; k += stride) {
    int e = eidx[k], n = nidx[k];
    int pe = atomicSub(&ecnt[e], 1) - 1;
    enodes[eptr[e] + pe] = n;
    int pn = atomicSub(&ncnt[n], 1) - 1;
    nedges[nptr[n] + pn] = e;
  }
}

__global__ void dinv_kernel(float* __restrict__ D) {
  int i = blockIdx.x * blockDim.x + threadIdx.x;
  if (i < NN) { float d = D[i]; D[i] = (d > 0.0f) ? 1.0f / d : 0.0f; }
}

// ---------------- weight prep: bf16 split in MFMA-fragment-linear order ----------------
// Fragment order: idx g = (ksg*8 + ct)*64 + lane; element j: value W'[ksg*32+(lane>>4)*8+j][ct*16+(lane&15)]
// W_up [256][128] -> 8 ksg groups; 4096 groups total -> 16 blocks x 256 threads.
__global__ void wsplit_up_kernel(const float* __restrict__ W, ushort_t* __restrict__ Fh,
                                 ushort_t* __restrict__ Fl) {
  int g = blockIdx.x * 256 + threadIdx.x;      // [0, 4096)
  int ln = g & 63;
  int ct = (g >> 6) & 7;
  int ksg = g >> 9;
  int c = ct * 16 + (ln & 15);
  int k0 = ksg * 32 + (ln >> 4) * 8;
  #pragma unroll
  for (int j = 0; j < 8; ++j) {
    ushort_t h, l;
    split1(W[(size_t)(k0 + j) * HIDDIM + c], h, l);
    Fh[(size_t)g * 8 + j] = h;
    Fl[(size_t)g * 8 + j] = l;
  }
}

// BN-folded conv weight in fragment order (KDIM=128 -> 4 ksg, 2048 groups), plus b' = c @ Wc
__global__ void prep_kernel(const float* __restrict__ stats, const float* __restrict__ gamma,
    const float* __restrict__ beta, const float* __restrict__ Wc,
    ushort_t* __restrict__ Fh, ushort_t* __restrict__ Fl, float* __restrict__ bp) {
  __shared__ float al[128], cc[128];
  int t = threadIdx.x;  // 256 threads, 1 block
  if (t < 128) {
    float mu = stats[t] * (1.0f / NN);
    float var = fmaxf(stats[128 + t] * (1.0f / NN) - mu * mu, 0.0f);
    float a = gamma[t] * rsqrtf(var + EPSBN);
    al[t] = a;
    cc[t] = beta[t] - mu * a;
  }
  __syncthreads();
  for (int g = t; g < 2048; g += 256) {
    int ln = g & 63;
    int ct = (g >> 6) & 7;
    int ksg = g >> 9;
    int c = ct * 16 + (ln & 15);
    int k0 = ksg * 32 + (ln >> 4) * 8;
    #pragma unroll
    for (int j = 0; j < 8; ++j) {
      ushort_t h, l;
      split1(al[k0 + j] * Wc[(k0 + j) * 128 + c], h, l);
      Fh[(size_t)g * 8 + j] = h;
      Fl[(size_t)g * 8 + j] = l;
    }
  }
  if (t < 128) {
    float b = 0.f;
    for (int k = 0; k < 128; ++k) b = fmaf(cc[k], Wc[k * 128 + t], b);
    bp[t] = b;
  }
}

// ---------------- MFMA GEMM v2: LDS-staged fragment-linear B, swapped operands ----------------
// Block: 4 waves x 16 rows = 64 rows, all 128 cols. Chunked over K in 64-k chunks (32KB LDS).
// mfma(Wfrag as A-op, Xfrag as B-op): lane l holds C[row = rt+(l&15)][col = ct*16+(l>>4)*4+r]
// -> float4 coalesced C stores. Same 3-term hi/lo split as before (bit-identical numerics).
template<int KDIM, bool RELU, bool DUP>
__global__ __launch_bounds__(256, 4) void mgemm_kernel(const float* __restrict__ A,
    const ushort_t* __restrict__ WFh, const ushort_t* __restrict__ WFl,
    const float* __restrict__ bias, float* __restrict__ out, float* __restrict__ out2,
    int nrows) {
  __shared__ ushort_t Bls[16384];          // 32KB: hi [0,8192) shorts, lo [8192,16384)
  const int t = threadIdx.x;
  const int lane = t & 63;
  const int wv = t >> 6;
  const int m = lane & 15;
  const int kg = lane >> 4;
  const int rt = blockIdx.x * 64 + wv * 16;

  f32x4 acc[8];
  #pragma unroll
  for (int ct = 0; ct < 8; ++ct) acc[ct] = (f32x4){0.f, 0.f, 0.f, 0.f};

  const int row0 = rt + m;
  const bool v0 = row0 < nrows;
  const float* a0p = A + (size_t)row0 * KDIM + kg * 8;

  for (int c2 = 0; c2 < KDIM / 64; ++c2) {
    if (c2) __syncthreads();               // previous chunk fully consumed
    // stage 16KB hi + 16KB lo, linear copy (conflict-free ds_write_b128)
    const uint4* sh = (const uint4*)(WFh + c2 * 8192);
    const uint4* sl = (const uint4*)(WFl + c2 * 8192);
    uint4* dh = (uint4*)Bls;
    uint4* dl = (uint4*)(Bls + 8192);
    #pragma unroll
    for (int i = 0; i < 4; ++i) {
      dh[i * 256 + t] = sh[i * 256 + t];
      dl[i * 256 + t] = sl[i * 256 + t];
    }
    __syncthreads();
    #pragma unroll
    for (int ks2 = 0; ks2 < 2; ++ks2) {
      int kof = c2 * 64 + ks2 * 32;
      float a0[8] = {0, 0, 0, 0, 0, 0, 0, 0};
      if (v0) {
        *(float4*)(a0) = *(const float4*)(a0p + kof);
        *(float4*)(a0 + 4) = *(const float4*)(a0p + kof + 4);
      }
      bf16x8 a0h, a0l;
      #pragma unroll
      for (int j = 0; j < 8; ++j) {
        ushort_t h, l;
        split1(a0[j], h, l);
        a0h[j] = (short)h;
        a0l[j] = (short)l;
      }
      #pragma unroll
      for (int ct = 0; ct < 8; ++ct) {
        int fo = ((ks2 * 8 + ct) * 64 + lane) * 8;
        bf16x8 bh = *(const bf16x8*)(Bls + fo);
        bf16x8 bl = *(const bf16x8*)(Bls + 8192 + fo);
        acc[ct] = __builtin_amdgcn_mfma_f32_16x16x32_bf16(bh, a0h, acc[ct], 0, 0, 0);
        acc[ct] = __builtin_amdgcn_mfma_f32_16x16x32_bf16(bl, a0h, acc[ct], 0, 0, 0);
        acc[ct] = __builtin_amdgcn_mfma_f32_16x16x32_bf16(bh, a0l, acc[ct], 0, 0, 0);
      }
    }
  }
  if (row0 < nrows) {
    float* o = out + (size_t)row0 * HIDDIM;
    #pragma unroll
    for (int ct = 0; ct < 8; ++ct) {
      float4 b4 = ((const float4*)bias)[ct * 4 + kg];
      float4 v;
      v.x = acc[ct][0] + b4.x;
      v.y = acc[ct][1] + b4.y;
      v.z = acc[ct][2] + b4.z;
      v.w = acc[ct][3] + b4.w;
      if (RELU) {
        v.x = fmaxf(v.x, 0.f); v.y = fmaxf(v.y, 0.f);
        v.z = fmaxf(v.z, 0.f); v.w = fmaxf(v.w, 0.f);
      }
      *(float4*)(o + ct * 16 + kg * 4) = v;
      if (DUP) *(float4*)(out2 + (size_t)row0 * HIDDIM + ct * 16 + kg * 4) = v;
    }
  }
}

// ---------------- per-column sum / sumsq for BatchNorm (layer 0 only) ----------------
__global__ __launch_bounds__(256) void stats_kernel(const float* __restrict__ x,
    float* __restrict__ out, int n) {
  __shared__ float lsum[128], lsq[128];
  int t = threadIdx.x;
  int lane = t & 63, wv = t >> 6;
  if (t < 128) { lsum[t] = 0.f; lsq[t] = 0.f; }
  __syncthreads();
  float sx = 0, sy = 0, qx = 0, qy = 0;
  const float2* x2 = (const float2*)x;
  for (int r = blockIdx.x * 4 + wv; r < n; r += gridDim.x * 4) {
    float2 v = x2[(size_t)r * 64 + lane];
    sx += v.x; sy += v.y; qx += v.x * v.x; qy += v.y * v.y;
  }
  atomicAdd(&lsum[2 * lane], sx);
  atomicAdd(&lsum[2 * lane + 1], sy);
  atomicAdd(&lsq[2 * lane], qx);
  atomicAdd(&lsq[2 * lane + 1], qy);
  __syncthreads();
  if (t < 128) {
    atomicAdd(&out[t], lsum[t]);
    atomicAdd(&out[128 + t], lsq[t]);
  }
}

// ---------------- e = Binv * segsum(xw[nodes]) : one wave per edge ----------------
__global__ __launch_bounds__(256) void edge_agg_kernel(const float* __restrict__ xw,
    const int* __restrict__ eptr, const int* __restrict__ pend,
    const int* __restrict__ enodes, const float* __restrict__ binv,
    float* __restrict__ e2) {
  int gw = (blockIdx.x * 256 + threadIdx.x) >> 6;
  int lane = threadIdx.x & 63;
  int e = __builtin_amdgcn_readfirstlane(gw);
  if (e >= MM) return;
  int p0 = eptr[e], p1 = pend[e];
  const float2* xw2 = (const float2*)xw;
  float ax = 0, ay = 0, bx = 0, by = 0;
  int j = p0;
  for (; j + 2 <= p1; j += 2) {
    int n0 = enodes[j], n1 = enodes[j + 1];
    float2 v0 = xw2[(size_t)n0 * 64 + lane];
    float2 v1 = xw2[(size_t)n1 * 64 + lane];
    ax += v0.x; ay += v0.y; bx += v1.x; by += v1.y;
  }
  if (j < p1) {
    int n0 = enodes[j];
    float2 v0 = xw2[(size_t)n0 * 64 + lane];
    ax += v0.x; ay += v0.y;
  }
  float bi = binv[e];
  float2 r; r.x = (ax + bx) * bi; r.y = (ay + by) * bi;
  ((float2*)e2)[(size_t)e * 64 + lane] = r;
}

// ---------------- node update + fused BN stats for next layer ----------------
template<bool LAST>
__global__ __launch_bounds__(256) void node_agg_kernel(const float* __restrict__ e2,
    const int* __restrict__ nptr, const int* __restrict__ pend,
    const int* __restrict__ nedges, const float* __restrict__ dinv,
    const float* __restrict__ bconv, const float* __restrict__ wgate,
    const float* __restrict__ bgate, const float* __restrict__ x,
    float* __restrict__ xout, const float* __restrict__ idres, float* __restrict__ fout,
    float* __restrict__ stats_out) {
  __shared__ float ls[256];
  int t = threadIdx.x;
  int lane = t & 63, wv = t >> 6;
  ls[t] = 0.f;
  __syncthreads();
  float sx = 0, sy = 0, qx = 0, qy = 0;
  const float2* e22 = (const float2*)e2;
  for (int nid0 = blockIdx.x * 4 + wv; nid0 < NN; nid0 += gridDim.x * 4) {
    int nid = __builtin_amdgcn_readfirstlane(nid0);
    int p0 = nptr[nid], p1 = pend[nid];
    float ax = 0, ay = 0;
    for (int j = p0; j < p1; ++j) {
      int e = nedges[j];
      float2 v = e22[(size_t)e * 64 + lane];
      ax += v.x; ay += v.y;
    }
    float di = dinv[nid];
    float2 xv = ((const float2*)x)[(size_t)nid * 64 + lane];
    float2 wg = ((const float2*)wgate)[lane];
    float part = xv.x * wg.x + xv.y * wg.y;
    #pragma unroll
    for (int off = 32; off >= 1; off >>= 1) part += __shfl_xor(part, off);
    float g = 1.0f / (1.0f + expf(-(part + bgate[0])));
    float2 bc = ((const float2*)bconv)[lane];
    float hx = fmaxf(fmaf(ax, di, bc.x), 0.0f);
    float hy = fmaxf(fmaf(ay, di, bc.y), 0.0f);
    float2 xn; xn.x = fmaf(hx, g, xv.x); xn.y = fmaf(hy, g, xv.y);
    if (LAST) {
      float2 idv = ((const float2*)idres)[(size_t)nid * 64 + lane];
      float2 o; o.x = 2.0f * xn.x + idv.x; o.y = 2.0f * xn.y + idv.y;
      ((float2*)fout)[(size_t)nid * 64 + lane] = o;
    } else {
      ((float2*)xout)[(size_t)nid * 64 + lane] = xn;
      sx += xn.x; sy += xn.y; qx += xn.x * xn.x; qy += xn.y * xn.y;
    }
  }
  if (!LAST) {
    atomicAdd(&ls[2 * lane], sx);
    atomicAdd(&ls[2 * lane + 1], sy);
    atomicAdd(&ls[128 + 2 * lane], qx);
    atomicAdd(&ls[128 + 2 * lane + 1], qy);
    __syncthreads();
    atomicAdd(&stats_out[t], ls[t]);
  }
}

extern "C" void kernel_launch(void* const* d_in, const int* in_sizes, int n_in,
                              void* d_out, int out_size, void* d_ws, size_t ws_size,
                              hipStream_t stream) {
  const float* X      = (const float*)d_in[0];
  const int*   nidx   = (const int*)d_in[1];
  const int*   eidx   = (const int*)d_in[2];
  const float* hw     = (const float*)d_in[3];
  const float* W_up   = (const float*)d_in[4];
  const float* b_up   = (const float*)d_in[5];
  const float* gamma  = (const float*)d_in[6];
  const float* beta   = (const float*)d_in[7];
  const float* W_conv = (const float*)d_in[8];
  const float* b_conv = (const float*)d_in[9];
  const float* W_gate = (const float*)d_in[10];
  const float* b_gate = (const float*)d_in[11];
  float* out = (float*)d_out;

  char* ws = (char*)d_ws;
  size_t off = 0;
  auto alloc = [&](size_t bytes) -> void* {
    void* p = ws + off;
    off = (off + bytes + 255) & ~(size_t)255;
    return p;
  };
  // ---- zero region (single memset) ----
  float* D     = (float*)alloc((size_t)NN * 4);
  int*   ecnt  = (int*)alloc((size_t)MM * 4);
  int*   ncnt  = (int*)alloc((size_t)NN * 4);
  int*   ctrs  = (int*)alloc(256);
  float* stats = (float*)alloc(3 * 256 * 4);
  size_t zero_bytes = off;
  // ---- rest ----
  int*   eptr   = (int*)alloc((size_t)MM * 4);
  int*   epend  = (int*)alloc((size_t)MM * 4);
  int*   nptr   = (int*)alloc((size_t)NN * 4);
  int*   npend  = (int*)alloc((size_t)NN * 4);
  float* Binv   = (float*)alloc((size_t)MM * 4);
  int*   enodes = (int*)alloc((size_t)KINC * 4);
  int*   nedges = (int*)alloc((size_t)KINC * 4);
  float* x      = (float*)alloc((size_t)NN * HIDDIM * 4);
  float* idr    = (float*)alloc((size_t)NN * HIDDIM * 4);
  float* e2     = (float*)alloc((size_t)MM * HIDDIM * 4);
  ushort_t* WupFh = (ushort_t*)alloc((size_t)HIDDIM * INDIM * 2);
  ushort_t* WupFl = (ushort_t*)alloc((size_t)HIDDIM * INDIM * 2);
  ushort_t* WFh   = (ushort_t*)alloc((size_t)HIDDIM * HIDDIM * 2);
  ushort_t* WFl   = (ushort_t*)alloc((size_t)HIDDIM * HIDDIM * 2);
  float* bp     = (float*)alloc((size_t)HIDDIM * 4);
  float* xw     = out;   // reuse output buffer as xW scratch (consumed before final write)

  hipMemsetAsync(d_ws, 0, zero_bytes, stream);
  hist_kernel<<<512, 256, 0, stream>>>(nidx, eidx, hw, ecnt, ncnt, D);
  base_kernel<<<(MM + 255) / 256, 256, 0, stream>>>(ecnt, eptr, epend, Binv, ctrs + 0, MM);
  base_kernel<<<(NN + 255) / 256, 256, 0, stream>>>(ncnt, nptr, npend, nullptr, ctrs + 1, NN);
  fill_kernel<<<512, 256, 0, stream>>>(nidx, eidx, ecnt, ncnt, eptr, nptr, enodes, nedges);
  dinv_kernel<<<(NN + 255) / 256, 256, 0, stream>>>(D);
  wsplit_up_kernel<<<16, 256, 0, stream>>>(W_up, WupFh, WupFl);

  mgemm_kernel<INDIM, true, true><<<(NN + 63) / 64, 256, 0, stream>>>(
      X, WupFh, WupFl, b_up, x, idr, NN);
  stats_kernel<<<256, 256, 0, stream>>>(x, stats + 0, NN);

  for (int i = 0; i < 3; ++i) {
    prep_kernel<<<1, 256, 0, stream>>>(stats + i * 256, gamma + i * 128, beta + i * 128,
                                       W_conv + (size_t)i * 128 * 128, WFh, WFl, bp);
    mgemm_kernel<HIDDIM, false, false><<<(NN + 63) / 64, 256, 0, stream>>>(
        x, WFh, WFl, bp, xw, nullptr, NN);
    edge_agg_kernel<<<MM / 4, 256, 0, stream>>>(xw, eptr, epend, enodes, Binv, e2);
    if (i < 2)
      node_agg_kernel<false><<<1280, 256, 0, stream>>>(e2, nptr, npend, nedges, D,
          b_conv + i * 128, W_gate + i * 128, b_gate + i, x, x, nullptr, nullptr,
          stats + (i + 1) * 256);
    else
      node_agg_kernel<true><<<1280, 256, 0, stream>>>(e2, nptr, npend, nedges, D,
          b_conv + i * 128, W_gate + i * 128, b_gate + i, x, nullptr, idr, out, nullptr);
  }
}

// Round 8
// 884.118 us; speedup vs baseline: 1.3088x; 1.0459x over previous
//
#include <hip/hip_runtime.h>
#include <math.h>

#define NN 100000
#define MM 20000
#define KINC 640000
#define INDIM 256
#define HIDDIM 128
#define EPSBN 1e-5f

typedef __attribute__((ext_vector_type(4))) float f32x4;
typedef __attribute__((ext_vector_type(8))) short bf16x8;
typedef unsigned short ushort_t;

// round-to-nearest-even fp32 -> bf16 bits
__device__ inline unsigned f2bf_bits(float f) {
  unsigned u = __float_as_uint(f);
  return u + 0x7FFFu + ((u >> 16) & 1u);
}
__device__ inline void split1(float f, ushort_t& hi, ushort_t& lo) {
  unsigned rh = f2bf_bits(f) & 0xFFFF0000u;
  hi = (ushort_t)(rh >> 16);
  float d = f - __uint_as_float(rh);
  lo = (ushort_t)(f2bf_bits(d) >> 16);
}

// ---------------- CSR build ----------------

__global__ void hist_kernel(const int* __restrict__ nidx, const int* __restrict__ eidx,
                            const float* __restrict__ w, int* __restrict__ ecnt,
                            int* __restrict__ ncnt, float* __restrict__ D) {
  int stride = gridDim.x * blockDim.x;
  for (int k = blockIdx.x * blockDim.x + threadIdx.x; k < KINC; k += stride) {
    int e = eidx[k], n = nidx[k];
    atomicAdd(&ecnt[e], 1);
    atomicAdd(&ncnt[n], 1);
    atomicAdd(&D[n], w[e]);
  }
}

__global__ void base_kernel(const int* __restrict__ cnt, int* __restrict__ ptr,
                            int* __restrict__ pend, float* __restrict__ binv,
                            int* __restrict__ counter, int len) {
  int i = blockIdx.x * blockDim.x + threadIdx.x;
  int lane = threadIdx.x & 63;
  int v = (i < len) ? cnt[i] : 0;
  int s = v;
  #pragma unroll
  for (int off = 1; off < 64; off <<= 1) {
    int t = __shfl_up(s, off);
    if (lane >= off) s += t;
  }
  int total = __shfl(s, 63);
  int base = 0;
  if (lane == 0) base = atomicAdd(counter, total);
  base = __shfl(base, 0);
  if (i < len) {
    ptr[i] = base + s - v;
    pend[i] = base + s;
    if (binv) binv[i] = (v > 0) ? 1.0f / (float)v : 0.0f;
  }
}

__global__ void fill_kernel(const int* __restrict__ nidx, const int* __restrict__ eidx,
                            int* __restrict__ ecnt, int* __restrict__ ncnt,
                            const int* __restrict__ eptr, const int* __restrict__ nptr,
                            int* __restrict__ enodes, int* __restrict__ nedges) {
  int stride = gridDim.x * blockDim.x;
  for (int k = blockIdx.x * blockDim.x + threadIdx.x; k < KINC; k += stride) {
    int e = eidx[k], n = nidx[k];
    int pe = atomicSub(&ecnt[e], 1) - 1;
    enodes[eptr[e] + pe] = n;
    int pn = atomicSub(&ncnt[n], 1) - 1;
    nedges[nptr[n] + pn] = e;
  }
}

__global__ void dinv_kernel(float* __restrict__ D) {
  int i = blockIdx.x * blockDim.x + threadIdx.x;
  if (i < NN) { float d = D[i]; D[i] = (d > 0.0f) ? 1.0f / d : 0.0f; }
}

// ---------------- weight prep: bf16 split in MFMA-fragment-linear order ----------------
__global__ void wsplit_up_kernel(const float* __restrict__ W, ushort_t* __restrict__ Fh,
                                 ushort_t* __restrict__ Fl) {
  int g = blockIdx.x * 256 + threadIdx.x;      // [0, 4096)
  int ln = g & 63;
  int ct = (g >> 6) & 7;
  int ksg = g >> 9;
  int c = ct * 16 + (ln & 15);
  int k0 = ksg * 32 + (ln >> 4) * 8;
  #pragma unroll
  for (int j = 0; j < 8; ++j) {
    ushort_t h, l;
    split1(W[(size_t)(k0 + j) * HIDDIM + c], h, l);
    Fh[(size_t)g * 8 + j] = h;
    Fl[(size_t)g * 8 + j] = l;
  }
}

__global__ void prep_kernel(const float* __restrict__ stats, const float* __restrict__ gamma,
    const float* __restrict__ beta, const float* __restrict__ Wc,
    ushort_t* __restrict__ Fh, ushort_t* __restrict__ Fl, float* __restrict__ bp) {
  __shared__ float al[128], cc[128];
  int t = threadIdx.x;  // 256 threads, 1 block
  if (t < 128) {
    float mu = stats[t] * (1.0f / NN);
    float var = fmaxf(stats[128 + t] * (1.0f / NN) - mu * mu, 0.0f);
    float a = gamma[t] * rsqrtf(var + EPSBN);
    al[t] = a;
    cc[t] = beta[t] - mu * a;
  }
  __syncthreads();
  for (int g = t; g < 2048; g += 256) {
    int ln = g & 63;
    int ct = (g >> 6) & 7;
    int ksg = g >> 9;
    int c = ct * 16 + (ln & 15);
    int k0 = ksg * 32 + (ln >> 4) * 8;
    #pragma unroll
    for (int j = 0; j < 8; ++j) {
      ushort_t h, l;
      split1(al[k0 + j] * Wc[(k0 + j) * 128 + c], h, l);
      Fh[(size_t)g * 8 + j] = h;
      Fl[(size_t)g * 8 + j] = l;
    }
  }
  if (t < 128) {
    float b = 0.f;
    for (int k = 0; k < 128; ++k) b = fmaf(cc[k], Wc[k * 128 + t], b);
    bp[t] = b;
  }
}

// ---------------- MFMA GEMM v2: LDS-staged fragment-linear B, swapped operands ----------------
template<int KDIM, bool RELU, bool DUP>
__global__ __launch_bounds__(256, 4) void mgemm_kernel(const float* __restrict__ A,
    const ushort_t* __restrict__ WFh, const ushort_t* __restrict__ WFl,
    const float* __restrict__ bias, float* __restrict__ out, float* __restrict__ out2,
    int nrows) {
  __shared__ ushort_t Bls[16384];          // 32KB: hi [0,8192) shorts, lo [8192,16384)
  const int t = threadIdx.x;
  const int lane = t & 63;
  const int wv = t >> 6;
  const int m = lane & 15;
  const int kg = lane >> 4;
  const int rt = blockIdx.x * 64 + wv * 16;

  f32x4 acc[8];
  #pragma unroll
  for (int ct = 0; ct < 8; ++ct) acc[ct] = (f32x4){0.f, 0.f, 0.f, 0.f};

  const int row0 = rt + m;
  const bool v0 = row0 < nrows;
  const float* a0p = A + (size_t)row0 * KDIM + kg * 8;

  for (int c2 = 0; c2 < KDIM / 64; ++c2) {
    if (c2) __syncthreads();               // previous chunk fully consumed
    const uint4* sh = (const uint4*)(WFh + c2 * 8192);
    const uint4* sl = (const uint4*)(WFl + c2 * 8192);
    uint4* dh = (uint4*)Bls;
    uint4* dl = (uint4*)(Bls + 8192);
    #pragma unroll
    for (int i = 0; i < 4; ++i) {
      dh[i * 256 + t] = sh[i * 256 + t];
      dl[i * 256 + t] = sl[i * 256 + t];
    }
    __syncthreads();
    #pragma unroll
    for (int ks2 = 0; ks2 < 2; ++ks2) {
      int kof = c2 * 64 + ks2 * 32;
      float a0[8] = {0, 0, 0, 0, 0, 0, 0, 0};
      if (v0) {
        *(float4*)(a0) = *(const float4*)(a0p + kof);
        *(float4*)(a0 + 4) = *(const float4*)(a0p + kof + 4);
      }
      bf16x8 a0h, a0l;
      #pragma unroll
      for (int j = 0; j < 8; ++j) {
        ushort_t h, l;
        split1(a0[j], h, l);
        a0h[j] = (short)h;
        a0l[j] = (short)l;
      }
      #pragma unroll
      for (int ct = 0; ct < 8; ++ct) {
        int fo = ((ks2 * 8 + ct) * 64 + lane) * 8;
        bf16x8 bh = *(const bf16x8*)(Bls + fo);
        bf16x8 bl = *(const bf16x8*)(Bls + 8192 + fo);
        acc[ct] = __builtin_amdgcn_mfma_f32_16x16x32_bf16(bh, a0h, acc[ct], 0, 0, 0);
        acc[ct] = __builtin_amdgcn_mfma_f32_16x16x32_bf16(bl, a0h, acc[ct], 0, 0, 0);
        acc[ct] = __builtin_amdgcn_mfma_f32_16x16x32_bf16(bh, a0l, acc[ct], 0, 0, 0);
      }
    }
  }
  if (row0 < nrows) {
    float* o = out + (size_t)row0 * HIDDIM;
    #pragma unroll
    for (int ct = 0; ct < 8; ++ct) {
      float4 b4 = ((const float4*)bias)[ct * 4 + kg];
      float4 v;
      v.x = acc[ct][0] + b4.x;
      v.y = acc[ct][1] + b4.y;
      v.z = acc[ct][2] + b4.z;
      v.w = acc[ct][3] + b4.w;
      if (RELU) {
        v.x = fmaxf(v.x, 0.f); v.y = fmaxf(v.y, 0.f);
        v.z = fmaxf(v.z, 0.f); v.w = fmaxf(v.w, 0.f);
      }
      *(float4*)(o + ct * 16 + kg * 4) = v;
      if (DUP) *(float4*)(out2 + (size_t)row0 * HIDDIM + ct * 16 + kg * 4) = v;
    }
  }
}

// ---------------- per-column sum / sumsq for BatchNorm (layer 0 only) ----------------
__global__ __launch_bounds__(256) void stats_kernel(const float* __restrict__ x,
    float* __restrict__ out, int n) {
  __shared__ float lsum[128], lsq[128];
  int t = threadIdx.x;
  int lane = t & 63, wv = t >> 6;
  if (t < 128) { lsum[t] = 0.f; lsq[t] = 0.f; }
  __syncthreads();
  float sx = 0, sy = 0, qx = 0, qy = 0;
  const float2* x2 = (const float2*)x;
  for (int r = blockIdx.x * 4 + wv; r < n; r += gridDim.x * 4) {
    float2 v = x2[(size_t)r * 64 + lane];
    sx += v.x; sy += v.y; qx += v.x * v.x; qy += v.y * v.y;
  }
  atomicAdd(&lsum[2 * lane], sx);
  atomicAdd(&lsum[2 * lane + 1], sy);
  atomicAdd(&lsq[2 * lane], qx);
  atomicAdd(&lsq[2 * lane + 1], qy);
  __syncthreads();
  if (t < 128) {
    atomicAdd(&out[t], lsum[t]);
    atomicAdd(&out[128 + t], lsq[t]);
  }
}

// ---------------- e = Binv * segsum(xw[nodes]) : one wave per edge ----------------
// Batched coalesced index load + shfl broadcast + 4 independent gathers in flight.
__global__ __launch_bounds__(256) void edge_agg_kernel(const float* __restrict__ xw,
    const int* __restrict__ eptr, const int* __restrict__ pend,
    const int* __restrict__ enodes, const float* __restrict__ binv,
    float* __restrict__ e2) {
  int gw = (blockIdx.x * 256 + threadIdx.x) >> 6;
  int lane = threadIdx.x & 63;
  int e = __builtin_amdgcn_readfirstlane(gw);
  if (e >= MM) return;
  int p0 = eptr[e], p1 = pend[e];
  const float2* xw2 = (const float2*)xw;
  float ax = 0, ay = 0, bx = 0, by = 0, cx = 0, cy = 0, dx = 0, dy = 0;
  for (int base = p0; base < p1; base += 64) {
    int cnt = min(64, p1 - base);
    int myn = (lane < cnt) ? enodes[base + lane] : 0;   // coalesced batch load
    int jj = 0;
    for (; jj + 4 <= cnt; jj += 4) {
      int n0 = __shfl(myn, jj);
      int n1 = __shfl(myn, jj + 1);
      int n2 = __shfl(myn, jj + 2);
      int n3 = __shfl(myn, jj + 3);
      float2 u0 = xw2[(size_t)n0 * 64 + lane];
      float2 u1 = xw2[(size_t)n1 * 64 + lane];
      float2 u2 = xw2[(size_t)n2 * 64 + lane];
      float2 u3 = xw2[(size_t)n3 * 64 + lane];
      ax += u0.x; ay += u0.y; bx += u1.x; by += u1.y;
      cx += u2.x; cy += u2.y; dx += u3.x; dy += u3.y;
    }
    for (; jj < cnt; ++jj) {
      int n0 = __shfl(myn, jj);
      float2 u0 = xw2[(size_t)n0 * 64 + lane];
      ax += u0.x; ay += u0.y;
    }
  }
  float bi = binv[e];
  float2 r; r.x = (ax + bx + cx + dx) * bi; r.y = (ay + by + cy + dy) * bi;
  ((float2*)e2)[(size_t)e * 64 + lane] = r;
}

// ---------------- node update + fused BN stats for next layer ----------------
template<bool LAST>
__global__ __launch_bounds__(256) void node_agg_kernel(const float* __restrict__ e2,
    const int* __restrict__ nptr, const int* __restrict__ pend,
    const int* __restrict__ nedges, const float* __restrict__ dinv,
    const float* __restrict__ bconv, const float* __restrict__ wgate,
    const float* __restrict__ bgate, const float* __restrict__ x,
    float* __restrict__ xout, const float* __restrict__ idres, float* __restrict__ fout,
    float* __restrict__ stats_out) {
  __shared__ float ls[256];
  int t = threadIdx.x;
  int lane = t & 63, wv = t >> 6;
  ls[t] = 0.f;
  __syncthreads();
  float sx = 0, sy = 0, qx = 0, qy = 0;
  const float2* e22 = (const float2*)e2;
  for (int nid0 = blockIdx.x * 4 + wv; nid0 < NN; nid0 += gridDim.x * 4) {
    int nid = __builtin_amdgcn_readfirstlane(nid0);
    int p0 = nptr[nid], p1 = pend[nid];
    float ax = 0, ay = 0, bx = 0, by = 0, cx = 0, cy = 0, dx = 0, dy = 0;
    for (int base = p0; base < p1; base += 64) {
      int cnt = min(64, p1 - base);
      int mye = (lane < cnt) ? nedges[base + lane] : 0;   // coalesced batch load
      int jj = 0;
      for (; jj + 4 <= cnt; jj += 4) {
        int e0 = __shfl(mye, jj);
        int e1 = __shfl(mye, jj + 1);
        int e2i = __shfl(mye, jj + 2);
        int e3 = __shfl(mye, jj + 3);
        float2 u0 = e22[(size_t)e0 * 64 + lane];
        float2 u1 = e22[(size_t)e1 * 64 + lane];
        float2 u2 = e22[(size_t)e2i * 64 + lane];
        float2 u3 = e22[(size_t)e3 * 64 + lane];
        ax += u0.x; ay += u0.y; bx += u1.x; by += u1.y;
        cx += u2.x; cy += u2.y; dx += u3.x; dy += u3.y;
      }
      for (; jj < cnt; ++jj) {
        int e0 = __shfl(mye, jj);
        float2 u0 = e22[(size_t)e0 * 64 + lane];
        ax += u0.x; ay += u0.y;
      }
    }
    float axs = ax + bx + cx + dx, ays = ay + by + cy + dy;
    float di = dinv[nid];
    float2 xv = ((const float2*)x)[(size_t)nid * 64 + lane];
    float2 wg = ((const float2*)wgate)[lane];
    float part = xv.x * wg.x + xv.y * wg.y;
    #pragma unroll
    for (int off = 32; off >= 1; off >>= 1) part += __shfl_xor(part, off);
    float g = 1.0f / (1.0f + expf(-(part + bgate[0])));
    float2 bc = ((const float2*)bconv)[lane];
    float hx = fmaxf(fmaf(axs, di, bc.x), 0.0f);
    float hy = fmaxf(fmaf(ays, di, bc.y), 0.0f);
    float2 xn; xn.x = fmaf(hx, g, xv.x); xn.y = fmaf(hy, g, xv.y);
    if (LAST) {
      float2 idv = ((const float2*)idres)[(size_t)nid * 64 + lane];
      float2 o; o.x = 2.0f * xn.x + idv.x; o.y = 2.0f * xn.y + idv.y;
      ((float2*)fout)[(size_t)nid * 64 + lane] = o;
    } else {
      ((float2*)xout)[(size_t)nid * 64 + lane] = xn;
      sx += xn.x; sy += xn.y; qx += xn.x * xn.x; qy += xn.y * xn.y;
    }
  }
  if (!LAST) {
    atomicAdd(&ls[2 * lane], sx);
    atomicAdd(&ls[2 * lane + 1], sy);
    atomicAdd(&ls[128 + 2 * lane], qx);
    atomicAdd(&ls[128 + 2 * lane + 1], qy);
    __syncthreads();
    atomicAdd(&stats_out[t], ls[t]);
  }
}

extern "C" void kernel_launch(void* const* d_in, const int* in_sizes, int n_in,
                              void* d_out, int out_size, void* d_ws, size_t ws_size,
                              hipStream_t stream) {
  const float* X      = (const float*)d_in[0];
  const int*   nidx   = (const int*)d_in[1];
  const int*   eidx   = (const int*)d_in[2];
  const float* hw     = (const float*)d_in[3];
  const float* W_up   = (const float*)d_in[4];
  const float* b_up   = (const float*)d_in[5];
  const float* gamma  = (const float*)d_in[6];
  const float* beta   = (const float*)d_in[7];
  const float* W_conv = (const float*)d_in[8];
  const float* b_conv = (const float*)d_in[9];
  const float* W_gate = (const float*)d_in[10];
  const float* b_gate = (const float*)d_in[11];
  float* out = (float*)d_out;

  char* ws = (char*)d_ws;
  size_t off = 0;
  auto alloc = [&](size_t bytes) -> void* {
    void* p = ws + off;
    off = (off + bytes + 255) & ~(size_t)255;
    return p;
  };
  // ---- zero region (single memset) ----
  float* D     = (float*)alloc((size_t)NN * 4);
  int*   ecnt  = (int*)alloc((size_t)MM * 4);
  int*   ncnt  = (int*)alloc((size_t)NN * 4);
  int*   ctrs  = (int*)alloc(256);
  float* stats = (float*)alloc(3 * 256 * 4);
  size_t zero_bytes = off;
  // ---- rest ----
  int*   eptr   = (int*)alloc((size_t)MM * 4);
  int*   epend  = (int*)alloc((size_t)MM * 4);
  int*   nptr   = (int*)alloc((size_t)NN * 4);
  int*   npend  = (int*)alloc((size_t)NN * 4);
  float* Binv   = (float*)alloc((size_t)MM * 4);
  int*   enodes = (int*)alloc((size_t)KINC * 4);
  int*   nedges = (int*)alloc((size_t)KINC * 4);
  float* x      = (float*)alloc((size_t)NN * HIDDIM * 4);
  float* idr    = (float*)alloc((size_t)NN * HIDDIM * 4);
  float* e2     = (float*)alloc((size_t)MM * HIDDIM * 4);
  ushort_t* WupFh = (ushort_t*)alloc((size_t)HIDDIM * INDIM * 2);
  ushort_t* WupFl = (ushort_t*)alloc((size_t)HIDDIM * INDIM * 2);
  ushort_t* WFh   = (ushort_t*)alloc((size_t)HIDDIM * HIDDIM * 2);
  ushort_t* WFl   = (ushort_t*)alloc((size_t)HIDDIM * HIDDIM * 2);
  float* bp     = (float*)alloc((size_t)HIDDIM * 4);
  float* xw     = out;   // reuse output buffer as xW scratch (consumed before final write)

  hipMemsetAsync(d_ws, 0, zero_bytes, stream);
  hist_kernel<<<512, 256, 0, stream>>>(nidx, eidx, hw, ecnt, ncnt, D);
  base_kernel<<<(MM + 255) / 256, 256, 0, stream>>>(ecnt, eptr, epend, Binv, ctrs + 0, MM);
  base_kernel<<<(NN + 255) / 256, 256, 0, stream>>>(ncnt, nptr, npend, nullptr, ctrs + 1, NN);
  fill_kernel<<<512, 256, 0, stream>>>(nidx, eidx, ecnt, ncnt, eptr, nptr, enodes, nedges);
  dinv_kernel<<<(NN + 255) / 256, 256, 0, stream>>>(D);
  wsplit_up_kernel<<<16, 256, 0, stream>>>(W_up, WupFh, WupFl);

  mgemm_kernel<INDIM, true, true><<<(NN + 63) / 64, 256, 0, stream>>>(
      X, WupFh, WupFl, b_up, x, idr, NN);
  stats_kernel<<<256, 256, 0, stream>>>(x, stats + 0, NN);

  for (int i = 0; i < 3; ++i) {
    prep_kernel<<<1, 256, 0, stream>>>(stats + i * 256, gamma + i * 128, beta + i * 128,
                                       W_conv + (size_t)i * 128 * 128, WFh, WFl, bp);
    mgemm_kernel<HIDDIM, false, false><<<(NN + 63) / 64, 256, 0, stream>>>(
        x, WFh, WFl, bp, xw, nullptr, NN);
    edge_agg_kernel<<<MM / 4, 256, 0, stream>>>(xw, eptr, epend, enodes, Binv, e2);
    if (i < 2)
      node_agg_kernel<false><<<1280, 256, 0, stream>>>(e2, nptr, npend, nedges, D,
          b_conv + i * 128, W_gate + i * 128, b_gate + i, x, x, nullptr, nullptr,
          stats + (i + 1) * 256);
    else
      node_agg_kernel<true><<<1280, 256, 0, stream>>>(e2, nptr, npend, nedges, D,
          b_conv + i * 128, W_gate + i * 128, b_gate + i, x, nullptr, idr, out, nullptr);
  }
}